// Round 7
// baseline (208.877 us; speedup 1.0000x reference)
//
#include <hip/hip_runtime.h>

// YOLOv1 loss — split design:
//   box region (ch 0..9, 1/3 of bytes): async-DMA staged to ~8 KB LDS,
//     per-cell compute after one barrier. 8 blocks/CU -> 100% occupancy cap.
//   cls region (ch 10..29, 2/3 of bytes): barrier-free register float4 stream,
//     obj weight read per-element from staged labels-ch4 in LDS.
// pred, labels: [B=16384, C=30, G=7, G=7] fp32. Output: scalar fp32.

constexpr int BATCH  = 16384;
constexpr int G      = 7;
constexpr int GG     = 49;
constexpr int IMG_F  = 30 * GG;          // 1470
constexpr int TPB    = 256;
constexpr int IPB    = 2;                // images per block (even base -> 16B aligned)
constexpr int SPAN_F = IPB * IMG_F;      // 2940 floats per tensor per block
constexpr int NBLK   = BATCH / IPB;      // 8192
// Stashes (float4 idx within the 735-f4 span):
//   even img: span f4 [0,124)    = floats [0,496)      (box [0,490) + cls 490..495)
//   odd  img: span f4 [367,491)  = floats [1468,1964)  = odd floats [-2,494)
// Cls stream: seg A (even) span f4 [124,367) = 243 f4; seg B (odd) [491,735) = 244 f4.
constexpr int STASH_F4 = 124;            // staged f4 per image per tensor
constexpr int ODD_F4_0 = 367;            // odd stash source start (span f4)
constexpr int SEGA_N   = 243;
constexpr int SEGB_N   = 244;
constexpr int CLS_N    = SEGA_N + SEGB_N;  // 487 f4-pairs per block

__device__ __forceinline__ float sq(float x) { return x * x; }

__device__ __forceinline__ void async_copy16(const float4* gsrc, float4* ldst_uniform) {
    __builtin_amdgcn_global_load_lds(
        (const __attribute__((address_space(1))) void*)gsrc,
        (__attribute__((address_space(3))) void*)ldst_uniform,
        16, 0, 0);
}

__global__ __launch_bounds__(TPB, 8) void yolo_loss_partial(
    const float* __restrict__ pred,
    const float* __restrict__ lab,
    float* __restrict__ ws)
{
    // stash[0]=pred-even, [1]=pred-odd, [2]=lab-even, [3]=lab-odd (128 f4 each, padded)
    __shared__ float4 stash[4][128];
    __shared__ float wsum[TPB / 64];

    const int t    = threadIdx.x;
    const int lane = t & 63;
    const int w    = t >> 6;
    const float4* P4 = (const float4*)(pred + (size_t)blockIdx.x * SPAN_F);
    const float4* L4 = (const float4*)(lab  + (size_t)blockIdx.x * SPAN_F);

    // ---- DMA-stage box regions: 8 groups of 64 f4; wave w takes groups w, w+4 ----
#pragma unroll
    for (int rep = 0; rep < 2; ++rep) {
        const int g  = w + rep * 4;         // 0..7 (wave-uniform)
        const int si = g >> 1;              // stash 0..3
        const int hf = g & 1;               // half 0/1
        const int k  = hf * 64 + lane;      // f4 within stash
        if (k < STASH_F4) {
            const float4* base = (si >= 2) ? L4 : P4;
            const int src = ((si & 1) ? ODD_F4_0 : 0) + k;
            async_copy16(base + src, &stash[si][hf * 64]);
        }
    }

    float acc = 0.0f;

    // ---- cls stream: barrier-free float4 loads; obj read from LDS (post-sync) ----
    // Load globals first (independent of LDS), sync once, then weight+accumulate.
    float4 cp[2], cl[2];
    int    ce[2], cim[2];
    bool   cv[2];
#pragma unroll
    for (int it = 0; it < 2; ++it) {
        const int j = t + it * TPB;
        cv[it] = j < CLS_N;
        int s, e, im;
        if (j < SEGA_N) { im = 0; s = STASH_F4 + j; e = 4 * s; }          // 496..1464
        else            { im = 1; s = (STASH_F4 + SEGA_N - SEGB_N) + j + SEGB_N; // 491+(j-243)
                          s = 248 + j; e = 4 * s - IMG_F; }               // 494..1466
        const int ss = cv[it] ? s : 0;
        cp[it] = P4[ss];
        cl[it] = L4[ss];
        ce[it] = e;
        cim[it] = im;
    }

    __syncthreads();   // DMA drain: stashes valid from here

    const float* F = (const float*)stash;  // pred: [0,1024); lab: [1024,2048)
    // labels ch4 float index: even img -> 1024+196+cell ; odd img -> 1536+2+196+cell

#pragma unroll
    for (int it = 0; it < 2; ++it) {
        if (!cv[it]) continue;
        const int e  = ce[it];
        const int im = cim[it];
        const int objbase = im ? (1536 + 2 + 4 * GG) : (1024 + 4 * GG);
        const int c0 = e % GG;
        const float pq[4] = {cp[it].x, cp[it].y, cp[it].z, cp[it].w};
        const float lq[4] = {cl[it].x, cl[it].y, cl[it].z, cl[it].w};
#pragma unroll
        for (int q = 0; q < 4; ++q) {
            int cq = c0 + q; if (cq >= GG) cq -= GG;
            const float ov = F[objbase + cq];
            const float d  = pq[q] - lq[q];
            acc += ((ov == 1.0f) ? 1.0f : 0.0f) * d * d;
        }
    }

    // ---- cls leftovers (12 floats/tensor outside the aligned stream, in LDS) ----
    if (t < 12) {
        // float idx into pred view F[]; labels at +1024.
        const int loff [12] = {490,491,492,493,494,495, 512,513, 1004,1005,1006,1007};
        const int lcell[12] = {0,1,2,3,4,5, 47,48, 0,1,2,3};
        const int limg [12] = {0,0,0,0,0,0, 0,0, 1,1,1,1};
        const int objbase = limg[t] ? (1536 + 2 + 4 * GG) : (1024 + 4 * GG);
        const float ov = F[objbase + lcell[t]];
        const float d  = F[loff[t]] - F[1024 + loff[t]];
        acc += ((ov == 1.0f) ? 1.0f : 0.0f) * d * d;
    }

    // ---- box loss: threads 0..97, one cell each, from LDS ----
    if (t < IPB * GG) {
        const int img  = t / GG;
        const int cell = t - img * GG;
        const int m    = cell / G;
        const int n    = cell - m * G;
        // pred stash: even base 0, odd base 512 with +2 skew; labels at +1024.
        const float* bp = F + (img ? (512 + 2) : 0);
        const float* bl = F + 1024 + (img ? (512 + 2) : 0);

        float pv[10];
#pragma unroll
        for (int c = 0; c < 10; ++c) pv[c] = bp[c * GG + cell];
        float lv[9];
#pragma unroll
        for (int c = 0; c < 9; ++c) lv[c] = bl[c * GG + cell];

        const float gx = (float)m, gy = (float)n;
        const float inv7 = 1.0f / 7.0f;

        const float cx1 = (pv[0] + gx) * inv7, cy1 = (pv[1] + gy) * inv7;
        const float hw1 = 0.5f * pv[2],        hh1 = 0.5f * pv[3];
        const float a1x1 = cx1 - hw1, a1y1 = cy1 - hh1, a1x2 = cx1 + hw1, a1y2 = cy1 + hh1;
        const float cx2 = (pv[5] + gx) * inv7, cy2 = (pv[6] + gy) * inv7;
        const float hw2 = 0.5f * pv[7],        hh2 = 0.5f * pv[8];
        const float a2x1 = cx2 - hw2, a2y1 = cy2 - hh2, a2x2 = cx2 + hw2, a2y2 = cy2 + hh2;
        const float cxg = (lv[0] + gx) * inv7, cyg = (lv[1] + gy) * inv7;
        const float hwg = 0.5f * lv[2],        hhg = 0.5f * lv[3];
        const float bx1 = cxg - hwg, by1 = cyg - hhg, bx2 = cxg + hwg, by2 = cyg + hhg;

        const float area_g = (bx2 - bx1) * (by2 - by1);

        float ix1 = fmaxf(a1x1, bx1), iy1 = fmaxf(a1y1, by1);
        float ix2 = fminf(a1x2, bx2), iy2 = fminf(a1y2, by2);
        float inter1 = fmaxf(ix2 - ix1, 0.0f) * fmaxf(iy2 - iy1, 0.0f);
        float area1  = (a1x2 - a1x1) * (a1y2 - a1y1);
        float iou1 = (inter1 > 0.0f) ? inter1 / (area1 + area_g - inter1) : 0.0f;

        ix1 = fmaxf(a2x1, bx1); iy1 = fmaxf(a2y1, by1);
        ix2 = fminf(a2x2, bx2); iy2 = fminf(a2y2, by2);
        float inter2 = fmaxf(ix2 - ix1, 0.0f) * fmaxf(iy2 - iy1, 0.0f);
        float area2  = (a2x2 - a2x1) * (a2y2 - a2y1);
        float iou2 = (inter2 > 0.0f) ? inter2 / (area2 + area_g - inter2) : 0.0f;

        const bool resp1 = iou1 > iou2;
        const float obj = (lv[4] == 1.0f) ? 1.0f : 0.0f;

        const float coor1 = sq(pv[0] - lv[0]) + sq(pv[1] - lv[1])
                          + sq(sqrtf(pv[2]) - sqrtf(lv[2])) + sq(sqrtf(pv[3]) - sqrtf(lv[3]));
        const float coor2 = sq(pv[5] - lv[5]) + sq(pv[6] - lv[6])
                          + sq(sqrtf(pv[7]) - sqrtf(lv[7])) + sq(sqrtf(pv[8]) - sqrtf(lv[8]));
        const float coor = resp1 ? coor1 : coor2;

        const float e1 = sq(pv[4] - iou1);
        const float e2 = sq(pv[9] - iou2);
        const float obj_conf   = resp1 ? e1 : e2;
        const float noobj_resp = resp1 ? e2 : e1;

        acc += obj * (5.0f * coor + obj_conf + 0.5f * noobj_resp)
             + (1.0f - obj) * 0.5f * (pv[4] * pv[4] + pv[9] * pv[9]);
    }

    // ---- reduce: wave shuffle -> LDS -> one partial per block ----
#pragma unroll
    for (int off = 32; off > 0; off >>= 1) acc += __shfl_down(acc, off, 64);
    if (lane == 0) wsum[w] = acc;
    __syncthreads();
    if (t == 0) ws[blockIdx.x] = wsum[0] + wsum[1] + wsum[2] + wsum[3];
}

__global__ __launch_bounds__(TPB) void yolo_loss_final(
    const float* __restrict__ ws, float* __restrict__ out)
{
    const int t = threadIdx.x;
    const float4* w4 = (const float4*)ws;
    float4 a = make_float4(0.f, 0.f, 0.f, 0.f);
#pragma unroll
    for (int j = 0; j < NBLK / 4 / TPB; ++j) {   // 8192/4/256 = 8 exact
        float4 x = w4[t + j * TPB];
        a.x += x.x; a.y += x.y; a.z += x.z; a.w += x.w;
    }
    float v = (a.x + a.y) + (a.z + a.w);
#pragma unroll
    for (int off = 32; off > 0; off >>= 1) v += __shfl_down(v, off, 64);

    __shared__ float wsum[TPB / 64];
    const int lane = t & 63;
    const int wid  = t >> 6;
    if (lane == 0) wsum[wid] = v;
    __syncthreads();
    if (t == 0) {
        // faithful reference quirk: divide by (N-1) == 6, not batch size
        out[0] = (wsum[0] + wsum[1] + wsum[2] + wsum[3]) * (1.0f / 6.0f);
    }
}

extern "C" void kernel_launch(void* const* d_in, const int* in_sizes, int n_in,
                              void* d_out, int out_size, void* d_ws, size_t ws_size,
                              hipStream_t stream) {
    const float* pred = (const float*)d_in[0];
    const float* lab  = (const float*)d_in[1];
    float* ws  = (float*)d_ws;
    float* out = (float*)d_out;

    yolo_loss_partial<<<NBLK, TPB, 0, stream>>>(pred, lab, ws);
    yolo_loss_final<<<1, TPB, 0, stream>>>(ws, out);
}